// Round 8
// baseline (1213.499 us; speedup 1.0000x reference)
//
#include <hip/hip_runtime.h>
#include <stdint.h>

typedef __bf16 bf16;
typedef bf16 bf16x8 __attribute__((ext_vector_type(8)));
typedef float f32x4 __attribute__((ext_vector_type(4)));

static constexpr int B_    = 16;
static constexpr int C_IN  = 64;
static constexpr int H_    = 64;
static constexpr int W_    = 64;
static constexpr int C_OUT = 128;
static constexpr int NC    = 512;
static constexpr int PS    = 576;       // C_IN*3*3
static constexpr int L_    = H_ * W_;   // 4096
static constexpr int NR    = B_ * L_;   // 65536

#define DEVI __device__ __forceinline__

DEVI void gload_lds16(const void* g, void* l) {
  __builtin_amdgcn_global_load_lds(
      (const __attribute__((address_space(1))) uint32_t*)g,
      (__attribute__((address_space(3))) uint32_t*)l, 16, 0, 0);
}

// ---------------- prep kernels ----------------

__global__ void prep_w_kernel(const float* __restrict__ w, bf16* __restrict__ WB,
                              bf16* __restrict__ ccT) {
  int i = blockIdx.x * 256 + threadIdx.x;
  if (i < C_OUT * PS) WB[i] = (bf16)w[i];
  if (i < 64 * NC) ccT[(size_t)PS * NC + i] = (bf16)0.f;  // zero pad rows 576..639
}

__global__ void prep_cc_kernel(const float* __restrict__ cc, bf16* __restrict__ ccB,
                               bf16* __restrict__ ccT, float* __restrict__ cn) {
  int j = blockIdx.x;
  const float* src = cc + (size_t)j * PS;
  float s = 0.f;
  for (int p = threadIdx.x; p < PS; p += 256) {
    float v = src[p];
    bf16 bv = (bf16)v;
    ccB[(size_t)j * PS + p] = bv;
    ccT[(size_t)p * NC + j] = bv;
    float fv = (float)bv;
    s += fv * fv;
  }
  for (int o = 32; o; o >>= 1) s += __shfl_xor(s, o);
  __shared__ float red[4];
  int lane = threadIdx.x & 63, wid = threadIdx.x >> 6;
  if (lane == 0) red[wid] = s;
  __syncthreads();
  if (threadIdx.x == 0) cn[j] = red[0] + red[1] + red[2] + red[3];
}

// Fused patch + rownorm: one wave per row. flat[n,p] = x[b,c,h+kh-1,w+kw-1],
// p = c*9+kh*3+kw, n = b*4096+h*64+w. rn[n] = sum_p flat_bf16[n,p]^2; rsum[n]=0.
__global__ void patch_kernel(const float* __restrict__ x, bf16* __restrict__ flatB,
                             float* __restrict__ rn, float* __restrict__ rsum) {
  int wid = threadIdx.x >> 6, lane = threadIdx.x & 63;
  int row = blockIdx.x * 4 + wid;
  int b = row >> 12, l = row & 4095;
  int h = l >> 6, w = l & 63;
  const float* xb = x + (size_t)b * (C_IN * L_);
  bf16* outp = flatB + (size_t)row * PS;
  float s = 0.f;
  {
    int p0 = lane * 8;
    bf16x8 v;
#pragma unroll
    for (int q = 0; q < 8; q++) {
      int p = p0 + q;
      int c = p / 9, r9 = p - c * 9;
      int kh = r9 / 3, kw = r9 - kh * 3;
      int y = h + kh - 1, xx = w + kw - 1;
      float val = 0.f;
      if ((unsigned)y < 64u && (unsigned)xx < 64u) val = xb[c * L_ + y * W_ + xx];
      bf16 bv = (bf16)val;
      float fv = (float)bv;
      s += fv * fv;
      v[q] = bv;
    }
    *(bf16x8*)(outp + p0) = v;
  }
  if (lane < 8) {
    int p0 = 512 + lane * 8;
    bf16x8 v;
#pragma unroll
    for (int q = 0; q < 8; q++) {
      int p = p0 + q;
      int c = p / 9, r9 = p - c * 9;
      int kh = r9 / 3, kw = r9 - kh * 3;
      int y = h + kh - 1, xx = w + kw - 1;
      float val = 0.f;
      if ((unsigned)y < 64u && (unsigned)xx < 64u) val = xb[c * L_ + y * W_ + xx];
      bf16 bv = (bf16)val;
      float fv = (float)bv;
      s += fv * fv;
      v[q] = bv;
    }
    *(bf16x8*)(outp + p0) = v;
  }
  for (int o = 32; o; o >>= 1) s += __shfl_xor(s, o);
  if (lane == 0) { rn[row] = s; rsum[row] = 0.f; }
}

// VT[b][l'][p'] = final_b viewed as [576][4096] at [p'][l'], with boundary mask.
// grid (64, 9, B_)
__global__ void transpose_mask_kernel(const bf16* __restrict__ finalB, bf16* __restrict__ VT) {
  int b = blockIdx.z;
  int l0 = blockIdx.x * 64, p0 = blockIdx.y * 64;
  const bf16* src = finalB + (size_t)b * L_ * PS;
  bf16* dst = VT + (size_t)b * L_ * PS;
  __shared__ bf16 tile[64][72];
  for (int s = threadIdx.x; s < 512; s += 256) {
    int i = s >> 3, ch = s & 7;  // i: p-row in tile, ch: l-chunk
    bf16x8 v = *(const bf16x8*)(src + (size_t)(p0 + i) * L_ + l0 + ch * 8);
#pragma unroll
    for (int q = 0; q < 8; q++) tile[ch * 8 + q][i] = v[q];
  }
  __syncthreads();
  for (int s = threadIdx.x; s < 512; s += 256) {
    int r = s >> 3, c = s & 7;  // r: l-row in tile, c: p-chunk
    int l = l0 + r;
    int oh = l >> 6, ow = l & 63;
    bf16x8 v;
#pragma unroll
    for (int q = 0; q < 8; q++) {
      int p = p0 + c * 8 + q;
      int r9 = p % 9;
      int kh = r9 / 3, kw = r9 - kh * 3;
      bf16 val = tile[r][c * 8 + q];
      if ((oh == 0 && kh == 0) || (ow == 0 && kw == 0)) val = (bf16)0.f;
      v[q] = val;
    }
    *(bf16x8*)(dst + (size_t)l * PS + p0 + c * 8) = v;
  }
}

// ---------------- NT-GEMM: C[M,N] = A[M,K] * B[N,K]^T, round-4 structure ----------
// Single-buffer, 2 __syncthreads per K-step, 16 KB LDS, 56 VGPR.
// __launch_bounds__(256, 8): 8 blocks/CU resident (VGPR<=64, LDS 8x16=128KB) --
// latency hiding via TLP across blocks (m114 mechanism), not pipeline depth.
// EPI 1: fused softmax-numerator: E = exp(-t*dist) (bf16), atomicAdd row sums.
// EPI 2: final = (t*acc/rsum[row] + flat)/(t+1) -> bf16, in-place over flat.
// EPI 3: batched (z), acc + bias[row] -> fp32 out.
// GX>0: 1D grid, XCD-aware swizzle (n-tiles of one row-panel share an XCD).
template <int EPI, int GX = 0>
__global__ void __launch_bounds__(256, 8) gemm_nt(
    const bf16* __restrict__ A, int lda, const bf16* __restrict__ Bm, int ldb,
    int M, int N, int Kd,
    const float* __restrict__ e0, const float* __restrict__ e1,
    const float* __restrict__ e2, const bf16* flatB,
    float* outF, bf16* outB, int ldc) {
  int bx, by;
  if constexpr (GX > 0) {
    int b = blockIdx.x;
    int xcd = b & 7;
    int k = b >> 3;
    int ypx = (gridDim.x >> 3) / GX;   // row-panels per XCD
    bx = k % GX;
    by = xcd * ypx + k / GX;
  } else {
    bx = blockIdx.x;
    by = blockIdx.y;
  }
  if constexpr (EPI == 3) {
    size_t bz = blockIdx.z;
    Bm += bz * (size_t)L_ * PS;
    outF += bz * (size_t)C_OUT * L_;
  }
  __shared__ bf16 As[128 * 32];
  __shared__ bf16 Bs[128 * 32];
  const int tid = threadIdx.x;
  const int lane = tid & 63;
  const int wid = tid >> 6;
  const int wr = wid >> 1, wc = wid & 1;
  const int m0 = by * 128, n0 = bx * 128;

  const int srow = tid >> 2;       // staging row 0..63 (+64 for second issue)
  // bank-swizzled staging k-slot: slot s of row r holds k-chunk (s ^ ((r>>1)&3))
  const int sch = (((tid & 3) ^ ((srow >> 1) & 3)) * 8);
  const bf16* gA = A + (size_t)(m0 + srow) * lda + sch;
  const bf16* gB = Bm + (size_t)(n0 + srow) * ldb + sch;
  bf16* lA = As + tid * 8;
  bf16* lB = Bs + tid * 8;

  const int lrow = lane & 15;
  const int kq = lane >> 4;
  const int kqs = kq ^ ((lrow >> 1) & 3);  // swizzled read slot
  const int aoff = (wr * 64 + lrow) * 32 + kqs * 8;
  const int boff = (wc * 64 + lrow) * 32 + kqs * 8;

  f32x4 acc[4][4];
#pragma unroll
  for (int i = 0; i < 4; i++)
#pragma unroll
    for (int j = 0; j < 4; j++) acc[i][j] = f32x4{0.f, 0.f, 0.f, 0.f};

  const int nk = Kd >> 5;
  for (int kt = 0; kt < nk; ++kt) {
    __syncthreads();
    const bf16* ga = gA + kt * 32;
    const bf16* gb = gB + kt * 32;
    gload_lds16(ga, lA);
    gload_lds16(ga + (size_t)64 * lda, lA + 2048);
    gload_lds16(gb, lB);
    gload_lds16(gb + (size_t)64 * ldb, lB + 2048);
    __syncthreads();  // drains vmcnt -> LDS tile ready
    bf16x8 af[4], bfr[4];
#pragma unroll
    for (int i = 0; i < 4; i++) af[i] = *(const bf16x8*)(As + aoff + i * 16 * 32);
#pragma unroll
    for (int j = 0; j < 4; j++) bfr[j] = *(const bf16x8*)(Bs + boff + j * 16 * 32);
#pragma unroll
    for (int i = 0; i < 4; i++)
#pragma unroll
      for (int j = 0; j < 4; j++)
        acc[i][j] = __builtin_amdgcn_mfma_f32_16x16x32_bf16(af[i], bfr[j], acc[i][j], 0, 0, 0);
  }

  const int rb = m0 + wr * 64 + kq * 4;  // D row = (lane>>4)*4 + reg
  const int cb = n0 + wc * 64 + lrow;    // D col = lane&15
  if constexpr (EPI == 1) {
    // e0 = rn, e1 = cn, e2 = temp; outB = E (bf16), outF = rsum (fp32 atomics)
    float t = e2[0];
#pragma unroll
    for (int i = 0; i < 4; i++) {
      float rowsum[4] = {0.f, 0.f, 0.f, 0.f};
#pragma unroll
      for (int j = 0; j < 4; j++) {
        int col = cb + j * 16;
        float cnv = e1[col];
#pragma unroll
        for (int r = 0; r < 4; r++) {
          int row = rb + i * 16 + r;
          float d2 = e0[row] + cnv - 2.f * acc[i][j][r];
          float e = __expf(-t * sqrtf(fmaxf(d2, 0.f)));
          outB[(size_t)row * ldc + col] = (bf16)e;
          rowsum[r] += e;
        }
      }
#pragma unroll
      for (int r = 0; r < 4; r++) {
        float s = rowsum[r];
        s += __shfl_xor(s, 1);
        s += __shfl_xor(s, 2);
        s += __shfl_xor(s, 4);
        s += __shfl_xor(s, 8);
        if (lrow == 0) atomicAdd(outF + rb + i * 16 + r, s);
      }
    }
  } else if constexpr (EPI == 2) {
    // e0 = temp, e1 = rsum; flatB = flat (read), outB = flat (in-place write)
    float t = e0[0];
    float inv = 1.f / (t + 1.f);
#pragma unroll
    for (int i = 0; i < 4; i++) {
      float arow[4];
#pragma unroll
      for (int r = 0; r < 4; r++) arow[r] = t * inv / e1[rb + i * 16 + r];
#pragma unroll
      for (int j = 0; j < 4; j++) {
        int col = cb + j * 16;
        if (col < N) {
#pragma unroll
          for (int r = 0; r < 4; r++) {
            int row = rb + i * 16 + r;
            float fl = (float)flatB[(size_t)row * PS + col];
            float v = acc[i][j][r] * arow[r] + fl * inv;
            outB[(size_t)row * ldc + col] = (bf16)v;
          }
        }
      }
    }
  } else {
    // e0 = bias; outF = out
#pragma unroll
    for (int i = 0; i < 4; i++) {
#pragma unroll
      for (int j = 0; j < 4; j++) {
        int col = cb + j * 16;
#pragma unroll
        for (int r = 0; r < 4; r++) {
          int row = rb + i * 16 + r;
          outF[(size_t)row * ldc + col] = acc[i][j][r] + e0[row];
        }
      }
    }
  }
}

// ---------------- launch ----------------

extern "C" void kernel_launch(void* const* d_in, const int* in_sizes, int n_in,
                              void* d_out, int out_size, void* d_ws, size_t ws_size,
                              hipStream_t stream) {
  (void)in_sizes; (void)n_in; (void)out_size; (void)ws_size;
  const float* x    = (const float*)d_in[0];
  const float* cc   = (const float*)d_in[1];
  const float* tp   = (const float*)d_in[2];
  const float* w    = (const float*)d_in[3];
  const float* bias = (const float*)d_in[4];
  float* out = (float*)d_out;

  char* ws = (char*)d_ws;
  size_t off = 0;
  auto alloc = [&](size_t bytes) {
    char* p = ws + off;
    off += (bytes + 255) & ~(size_t)255;
    return p;
  };
  // small persistent buffers
  bf16* ccB   = (bf16*)alloc((size_t)NC * PS * 2);        // 0.59 MB
  bf16* ccT   = (bf16*)alloc((size_t)640 * NC * 2);       // 0.66 MB (576 rows + 64 zero pad)
  float* cn   = (float*)alloc((size_t)NC * 4);
  bf16* WB    = (bf16*)alloc((size_t)C_OUT * PS * 2);     // 0.15 MB
  float* rn   = (float*)alloc((size_t)NR * 4);            // 0.26 MB
  float* rsum = (float*)alloc((size_t)NR * 4);            // 0.26 MB
  bf16* flatB = (bf16*)alloc((size_t)NR * PS * 2);        // 75.5 MB (final written in-place)
  char* Ereg  = alloc((size_t)NR * PS * 2);               // 75.5 MB region: E (65536x512) then VT
  bf16* E  = (bf16*)Ereg;
  bf16* VT = (bf16*)Ereg;
  // total ~= 153 MB  (ws_size = 256 MiB)

  prep_w_kernel<<<dim3(288), dim3(256), 0, stream>>>(w, WB, ccT);
  prep_cc_kernel<<<dim3(NC), dim3(256), 0, stream>>>(cc, ccB, ccT, cn);
  patch_kernel<<<dim3(NR / 4), dim3(256), 0, stream>>>(x, flatB, rn, rsum);
  // GEMM1 (+softmax numerator): E = exp(-t*sqrt(max(rn+cn-2*flat@cc^T,0))), rsum += rows
  gemm_nt<1, 4><<<dim3((NC / 128) * (NR / 128)), dim3(256), 0, stream>>>(
      flatB, PS, ccB, PS, NR, NC, PS, rn, cn, tp, nullptr, rsum, E, NC);
  // GEMM2: flat <- (t*(E@cc)/rsum + flat)/(t+1)   (in-place)
  gemm_nt<2, 5><<<dim3(5 * (NR / 128)), dim3(256), 0, stream>>>(
      E, NC, ccT, NC, NR, PS, NC, tp, rsum, nullptr, flatB, nullptr, flatB, PS);
  transpose_mask_kernel<<<dim3(64, 9, B_), dim3(256), 0, stream>>>(flatB, VT);
  // GEMM3 (batched): out[b] = W' @ Vmask_b + bias
  gemm_nt<3><<<dim3(L_ / 128, 1, B_), dim3(256), 0, stream>>>(
      WB, PS, VT, PS, C_OUT, L_, PS, bias, nullptr, nullptr, nullptr, out, nullptr, L_);
}

// Round 9
// 302.788 us; speedup vs baseline: 4.0077x; 4.0077x over previous
//
#include <hip/hip_runtime.h>
#include <stdint.h>

typedef __bf16 bf16;
typedef bf16 bf16x8 __attribute__((ext_vector_type(8)));
typedef float f32x4 __attribute__((ext_vector_type(4)));

static constexpr int B_    = 16;
static constexpr int C_IN  = 64;
static constexpr int H_    = 64;
static constexpr int W_    = 64;
static constexpr int C_OUT = 128;
static constexpr int NC    = 512;
static constexpr int PS    = 576;       // C_IN*3*3
static constexpr int L_    = H_ * W_;   // 4096
static constexpr int NR    = B_ * L_;   // 65536

#define DEVI __device__ __forceinline__

DEVI void gload_lds16(const void* g, void* l) {
  __builtin_amdgcn_global_load_lds(
      (const __attribute__((address_space(1))) uint32_t*)g,
      (__attribute__((address_space(3))) uint32_t*)l, 16, 0, 0);
}

// ---------------- prep kernels ----------------

__global__ void prep_w_kernel(const float* __restrict__ w, bf16* __restrict__ WB,
                              bf16* __restrict__ ccT) {
  int i = blockIdx.x * 256 + threadIdx.x;
  if (i < C_OUT * PS) WB[i] = (bf16)w[i];
  if (i < 64 * NC) ccT[(size_t)PS * NC + i] = (bf16)0.f;  // zero pad rows 576..639
}

__global__ void prep_cc_kernel(const float* __restrict__ cc, bf16* __restrict__ ccB,
                               bf16* __restrict__ ccT, float* __restrict__ cn) {
  int j = blockIdx.x;
  const float* src = cc + (size_t)j * PS;
  float s = 0.f;
  for (int p = threadIdx.x; p < PS; p += 256) {
    float v = src[p];
    bf16 bv = (bf16)v;
    ccB[(size_t)j * PS + p] = bv;
    ccT[(size_t)p * NC + j] = bv;
    float fv = (float)bv;
    s += fv * fv;
  }
  for (int o = 32; o; o >>= 1) s += __shfl_xor(s, o);
  __shared__ float red[4];
  int lane = threadIdx.x & 63, wid = threadIdx.x >> 6;
  if (lane == 0) red[wid] = s;
  __syncthreads();
  if (threadIdx.x == 0) cn[j] = red[0] + red[1] + red[2] + red[3];
}

// Fused patch + rownorm: one wave per row. flat[n,p] = x[b,c,h+kh-1,w+kw-1],
// p = c*9+kh*3+kw, n = b*4096+h*64+w. rn[n] = sum_p flat_bf16[n,p]^2; rsum[n]=0.
__global__ void patch_kernel(const float* __restrict__ x, bf16* __restrict__ flatB,
                             float* __restrict__ rn, float* __restrict__ rsum) {
  int wid = threadIdx.x >> 6, lane = threadIdx.x & 63;
  int row = blockIdx.x * 4 + wid;
  int b = row >> 12, l = row & 4095;
  int h = l >> 6, w = l & 63;
  const float* xb = x + (size_t)b * (C_IN * L_);
  bf16* outp = flatB + (size_t)row * PS;
  float s = 0.f;
  {
    int p0 = lane * 8;
    bf16x8 v;
#pragma unroll
    for (int q = 0; q < 8; q++) {
      int p = p0 + q;
      int c = p / 9, r9 = p - c * 9;
      int kh = r9 / 3, kw = r9 - kh * 3;
      int y = h + kh - 1, xx = w + kw - 1;
      float val = 0.f;
      if ((unsigned)y < 64u && (unsigned)xx < 64u) val = xb[c * L_ + y * W_ + xx];
      bf16 bv = (bf16)val;
      float fv = (float)bv;
      s += fv * fv;
      v[q] = bv;
    }
    *(bf16x8*)(outp + p0) = v;
  }
  if (lane < 8) {
    int p0 = 512 + lane * 8;
    bf16x8 v;
#pragma unroll
    for (int q = 0; q < 8; q++) {
      int p = p0 + q;
      int c = p / 9, r9 = p - c * 9;
      int kh = r9 / 3, kw = r9 - kh * 3;
      int y = h + kh - 1, xx = w + kw - 1;
      float val = 0.f;
      if ((unsigned)y < 64u && (unsigned)xx < 64u) val = xb[c * L_ + y * W_ + xx];
      bf16 bv = (bf16)val;
      float fv = (float)bv;
      s += fv * fv;
      v[q] = bv;
    }
    *(bf16x8*)(outp + p0) = v;
  }
  for (int o = 32; o; o >>= 1) s += __shfl_xor(s, o);
  if (lane == 0) { rn[row] = s; rsum[row] = 0.f; }
}

// VT[b][l'][p'] = final_b viewed as [576][4096] at [p'][l'], with boundary mask.
// grid (64, 9, B_)
__global__ void transpose_mask_kernel(const bf16* __restrict__ finalB, bf16* __restrict__ VT) {
  int b = blockIdx.z;
  int l0 = blockIdx.x * 64, p0 = blockIdx.y * 64;
  const bf16* src = finalB + (size_t)b * L_ * PS;
  bf16* dst = VT + (size_t)b * L_ * PS;
  __shared__ bf16 tile[64][72];
  for (int s = threadIdx.x; s < 512; s += 256) {
    int i = s >> 3, ch = s & 7;  // i: p-row in tile, ch: l-chunk
    bf16x8 v = *(const bf16x8*)(src + (size_t)(p0 + i) * L_ + l0 + ch * 8);
#pragma unroll
    for (int q = 0; q < 8; q++) tile[ch * 8 + q][i] = v[q];
  }
  __syncthreads();
  for (int s = threadIdx.x; s < 512; s += 256) {
    int r = s >> 3, c = s & 7;  // r: l-row in tile, c: p-chunk
    int l = l0 + r;
    int oh = l >> 6, ow = l & 63;
    bf16x8 v;
#pragma unroll
    for (int q = 0; q < 8; q++) {
      int p = p0 + c * 8 + q;
      int r9 = p % 9;
      int kh = r9 / 3, kw = r9 - kh * 3;
      bf16 val = tile[r][c * 8 + q];
      if ((oh == 0 && kh == 0) || (ow == 0 && kw == 0)) val = (bf16)0.f;
      v[q] = val;
    }
    *(bf16x8*)(dst + (size_t)l * PS + p0 + c * 8) = v;
  }
}

// ---------------- NT-GEMM: C[M,N] = A[M,K] * B[N,K]^T ----------------
// Round-4 skeleton (single-buffer, 2 __syncthreads per K-step) with BK=64:
// half as many K-steps -> half as many vmcnt(0) drain stalls (the measured
// 65% of cycles). LDS 32 KB/block (4 blocks/CU by LDS); regs in the <=128
// bucket (launch_bounds(256,4); round-8 proved (256,8) caps regs at 64 and
// spills the accumulator to scratch -- never again).
// LDS layout: row-major [128][64], 8x16B slots/row; slot s of row r holds
// global k-chunk (s ^ (r&7)) -- write side via pre-swizzled global source
// (gload_lds dest linear), read side applies the same XOR. 2-way conflicts.
// EPI 1: fused softmax-numerator: E = exp(-t*dist) (bf16), atomicAdd row sums.
// EPI 2: final = (t*acc/rsum[row] + flat)/(t+1) -> bf16, in-place over flat.
// EPI 3: batched (z), acc + bias[row] -> fp32 out.
// GX>0: 1D grid, XCD-aware swizzle (n-tiles of one row-panel share an XCD).
template <int EPI, int GX = 0>
__global__ void __launch_bounds__(256, 4) gemm_nt(
    const bf16* __restrict__ A, int lda, const bf16* __restrict__ Bm, int ldb,
    int M, int N, int Kd,
    const float* __restrict__ e0, const float* __restrict__ e1,
    const float* __restrict__ e2, const bf16* flatB,
    float* outF, bf16* outB, int ldc) {
  int bx, by;
  if constexpr (GX > 0) {
    int b = blockIdx.x;
    int xcd = b & 7;
    int k = b >> 3;
    int ypx = (gridDim.x >> 3) / GX;   // row-panels per XCD
    bx = k % GX;
    by = xcd * ypx + k / GX;
  } else {
    bx = blockIdx.x;
    by = blockIdx.y;
  }
  if constexpr (EPI == 3) {
    size_t bz = blockIdx.z;
    Bm += bz * (size_t)L_ * PS;
    outF += bz * (size_t)C_OUT * L_;
  }
  __shared__ bf16 As[128 * 64];   // 16 KB
  __shared__ bf16 Bs[128 * 64];   // 16 KB
  const int tid = threadIdx.x;
  const int lane = tid & 63;
  const int wid = tid >> 6;
  const int wr = wid >> 1, wc = wid & 1;
  const int m0 = by * 128, n0 = bx * 128;

  // staging: thread t covers row r = t>>3 (+32 per issue q), 16B slot s = t&7.
  // source k-chunk pre-inverse-swizzled: chunk = s ^ (r&7).
  const int srow = tid >> 3;
  const int sch = ((tid & 7) ^ (srow & 7)) * 8;
  const bf16* gA = A + (size_t)(m0 + srow) * lda + sch;
  const bf16* gB = Bm + (size_t)(n0 + srow) * ldb + sch;
  bf16* lA = As + tid * 8;
  bf16* lB = Bs + tid * 8;

  const int lrow = lane & 15;
  const int kq = lane >> 4;          // k-quarter within a 32-wide half
  const int axor = lrow & 7;         // read-side slot XOR (row & 7)
  const int arow = (wr * 64 + lrow) * 64;
  const int brow = (wc * 64 + lrow) * 64;

  f32x4 acc[4][4];
#pragma unroll
  for (int i = 0; i < 4; i++)
#pragma unroll
    for (int j = 0; j < 4; j++) acc[i][j] = f32x4{0.f, 0.f, 0.f, 0.f};

  const int nk = Kd >> 6;
  for (int kt = 0; kt < nk; ++kt) {
    __syncthreads();
    const bf16* ga = gA + kt * 64;
    const bf16* gb = gB + kt * 64;
#pragma unroll
    for (int q = 0; q < 4; ++q) {
      gload_lds16(ga + (size_t)(q * 32) * lda, lA + q * 2048);
      gload_lds16(gb + (size_t)(q * 32) * ldb, lB + q * 2048);
    }
    __syncthreads();  // drains vmcnt -> LDS tile ready
#pragma unroll
    for (int h = 0; h < 2; ++h) {
      const int cs = ((h * 4 + kq) ^ axor) * 8;   // swizzled slot for this k-half
      bf16x8 af[4], bfr[4];
#pragma unroll
      for (int i = 0; i < 4; i++) af[i] = *(const bf16x8*)(As + arow + i * 1024 + cs);
#pragma unroll
      for (int j = 0; j < 4; j++) bfr[j] = *(const bf16x8*)(Bs + brow + j * 1024 + cs);
#pragma unroll
      for (int i = 0; i < 4; i++)
#pragma unroll
        for (int j = 0; j < 4; j++)
          acc[i][j] = __builtin_amdgcn_mfma_f32_16x16x32_bf16(af[i], bfr[j], acc[i][j], 0, 0, 0);
    }
  }

  const int rb = m0 + wr * 64 + kq * 4;  // D row = (lane>>4)*4 + reg
  const int cb = n0 + wc * 64 + lrow;    // D col = lane&15
  if constexpr (EPI == 1) {
    // e0 = rn, e1 = cn, e2 = temp; outB = E (bf16), outF = rsum (fp32 atomics)
    float t = e2[0];
#pragma unroll
    for (int i = 0; i < 4; i++) {
      float rowsum[4] = {0.f, 0.f, 0.f, 0.f};
#pragma unroll
      for (int j = 0; j < 4; j++) {
        int col = cb + j * 16;
        float cnv = e1[col];
#pragma unroll
        for (int r = 0; r < 4; r++) {
          int row = rb + i * 16 + r;
          float d2 = e0[row] + cnv - 2.f * acc[i][j][r];
          float e = __expf(-t * sqrtf(fmaxf(d2, 0.f)));
          outB[(size_t)row * ldc + col] = (bf16)e;
          rowsum[r] += e;
        }
      }
#pragma unroll
      for (int r = 0; r < 4; r++) {
        float s = rowsum[r];
        s += __shfl_xor(s, 1);
        s += __shfl_xor(s, 2);
        s += __shfl_xor(s, 4);
        s += __shfl_xor(s, 8);
        if (lrow == 0) atomicAdd(outF + rb + i * 16 + r, s);
      }
    }
  } else if constexpr (EPI == 2) {
    // e0 = temp, e1 = rsum; flatB = flat (read), outB = flat (in-place write)
    float t = e0[0];
    float inv = 1.f / (t + 1.f);
#pragma unroll
    for (int i = 0; i < 4; i++) {
      float arw[4];
#pragma unroll
      for (int r = 0; r < 4; r++) arw[r] = t * inv / e1[rb + i * 16 + r];
#pragma unroll
      for (int j = 0; j < 4; j++) {
        int col = cb + j * 16;
        if (col < N) {
#pragma unroll
          for (int r = 0; r < 4; r++) {
            int row = rb + i * 16 + r;
            float fl = (float)flatB[(size_t)row * PS + col];
            float v = acc[i][j][r] * arw[r] + fl * inv;
            outB[(size_t)row * ldc + col] = (bf16)v;
          }
        }
      }
    }
  } else {
    // e0 = bias; outF = out
#pragma unroll
    for (int i = 0; i < 4; i++) {
#pragma unroll
      for (int j = 0; j < 4; j++) {
        int col = cb + j * 16;
#pragma unroll
        for (int r = 0; r < 4; r++) {
          int row = rb + i * 16 + r;
          outF[(size_t)row * ldc + col] = acc[i][j][r] + e0[row];
        }
      }
    }
  }
}

// ---------------- launch ----------------

extern "C" void kernel_launch(void* const* d_in, const int* in_sizes, int n_in,
                              void* d_out, int out_size, void* d_ws, size_t ws_size,
                              hipStream_t stream) {
  (void)in_sizes; (void)n_in; (void)out_size; (void)ws_size;
  const float* x    = (const float*)d_in[0];
  const float* cc   = (const float*)d_in[1];
  const float* tp   = (const float*)d_in[2];
  const float* w    = (const float*)d_in[3];
  const float* bias = (const float*)d_in[4];
  float* out = (float*)d_out;

  char* ws = (char*)d_ws;
  size_t off = 0;
  auto alloc = [&](size_t bytes) {
    char* p = ws + off;
    off += (bytes + 255) & ~(size_t)255;
    return p;
  };
  // small persistent buffers
  bf16* ccB   = (bf16*)alloc((size_t)NC * PS * 2);        // 0.59 MB
  bf16* ccT   = (bf16*)alloc((size_t)640 * NC * 2);       // 0.66 MB (576 rows + 64 zero pad)
  float* cn   = (float*)alloc((size_t)NC * 4);
  bf16* WB    = (bf16*)alloc((size_t)C_OUT * PS * 2);     // 0.15 MB
  float* rn   = (float*)alloc((size_t)NR * 4);            // 0.26 MB
  float* rsum = (float*)alloc((size_t)NR * 4);            // 0.26 MB
  bf16* flatB = (bf16*)alloc((size_t)NR * PS * 2);        // 75.5 MB (final written in-place)
  char* Ereg  = alloc((size_t)NR * PS * 2);               // 75.5 MB region: E (65536x512) then VT
  bf16* E  = (bf16*)Ereg;
  bf16* VT = (bf16*)Ereg;
  // total ~= 153 MB  (ws_size = 256 MiB)

  prep_w_kernel<<<dim3(288), dim3(256), 0, stream>>>(w, WB, ccT);
  prep_cc_kernel<<<dim3(NC), dim3(256), 0, stream>>>(cc, ccB, ccT, cn);
  patch_kernel<<<dim3(NR / 4), dim3(256), 0, stream>>>(x, flatB, rn, rsum);
  // GEMM1 (+softmax numerator): E = exp(-t*sqrt(max(rn+cn-2*flat@cc^T,0))), rsum += rows
  gemm_nt<1, 4><<<dim3((NC / 128) * (NR / 128)), dim3(256), 0, stream>>>(
      flatB, PS, ccB, PS, NR, NC, PS, rn, cn, tp, nullptr, rsum, E, NC);
  // GEMM2: flat <- (t*(E@cc)/rsum + flat)/(t+1)   (in-place)
  gemm_nt<2, 5><<<dim3(5 * (NR / 128)), dim3(256), 0, stream>>>(
      E, NC, ccT, NC, NR, PS, NC, tp, rsum, nullptr, flatB, nullptr, flatB, PS);
  transpose_mask_kernel<<<dim3(64, 9, B_), dim3(256), 0, stream>>>(flatB, VT);
  // GEMM3 (batched): out[b] = W' @ Vmask_b + bias
  gemm_nt<3><<<dim3(L_ / 128, 1, B_), dim3(256), 0, stream>>>(
      WB, PS, VT, PS, C_OUT, L_, PS, bias, nullptr, nullptr, nullptr, out, nullptr, L_);
}

// Round 10
// 250.263 us; speedup vs baseline: 4.8489x; 1.2099x over previous
//
#include <hip/hip_runtime.h>
#include <stdint.h>

typedef __bf16 bf16;
typedef bf16 bf16x2 __attribute__((ext_vector_type(2)));
typedef bf16 bf16x8 __attribute__((ext_vector_type(8)));
typedef float f32x4 __attribute__((ext_vector_type(4)));

static constexpr int B_    = 16;
static constexpr int C_IN  = 64;
static constexpr int H_    = 64;
static constexpr int W_    = 64;
static constexpr int C_OUT = 128;
static constexpr int NC    = 512;
static constexpr int PS    = 576;       // C_IN*3*3
static constexpr int L_    = H_ * W_;   // 4096
static constexpr int NR    = B_ * L_;   // 65536

#define DEVI __device__ __forceinline__

DEVI void gload_lds16(const void* g, void* l) {
  __builtin_amdgcn_global_load_lds(
      (const __attribute__((address_space(1))) uint32_t*)g,
      (__attribute__((address_space(3))) uint32_t*)l, 16, 0, 0);
}

// ---------------- prep kernels ----------------

__global__ void prep_w_kernel(const float* __restrict__ w, bf16* __restrict__ WB,
                              bf16* __restrict__ ccT) {
  int i = blockIdx.x * 256 + threadIdx.x;
  if (i < C_OUT * PS) WB[i] = (bf16)w[i];
  if (i < 64 * NC) ccT[(size_t)PS * NC + i] = (bf16)0.f;  // zero pad rows 576..639
}

__global__ void prep_cc_kernel(const float* __restrict__ cc, bf16* __restrict__ ccB,
                               bf16* __restrict__ ccT, float* __restrict__ cn) {
  int j = blockIdx.x;
  const float* src = cc + (size_t)j * PS;
  float s = 0.f;
  for (int p = threadIdx.x; p < PS; p += 256) {
    float v = src[p];
    bf16 bv = (bf16)v;
    ccB[(size_t)j * PS + p] = bv;
    ccT[(size_t)p * NC + j] = bv;
    float fv = (float)bv;
    s += fv * fv;
  }
  for (int o = 32; o; o >>= 1) s += __shfl_xor(s, o);
  __shared__ float red[4];
  int lane = threadIdx.x & 63, wid = threadIdx.x >> 6;
  if (lane == 0) red[wid] = s;
  __syncthreads();
  if (threadIdx.x == 0) cn[j] = red[0] + red[1] + red[2] + red[3];
}

// ---------------- patch v2: LDS-staged im2col + rownorm --------------------
// Block per (b,h). Stage x[b, :, h-1:h+2, :] as bf16 into LDS (row stride 66
// elements: bank = c*33+wo mod 32 -> conflict-free-ish; +2 base offset keeps
// the kw-1 underread in-bounds). Global reads: coalesced float4 rows. Writes:
// contiguous bf16x8 per (row, lane). rn = sum(bf16(v)^2), rsum = 0.
static constexpr int XS_STRIDE = 66;          // elements per c-row
static constexpr int XS_PLANE  = 64 * XS_STRIDE;  // 4224
static constexpr int XS_OFF    = 2;

__global__ void __launch_bounds__(256, 4) patch_kernel(
    const float* __restrict__ x, bf16* __restrict__ flatB,
    float* __restrict__ rn, float* __restrict__ rsum) {
  __shared__ bf16 xs[XS_OFF + 3 * XS_PLANE + 64];   // ~25.5 KB
  const int bh = blockIdx.x;
  const int b = bh >> 6, h = bh & 63;
  const size_t bOff = (size_t)b * (C_IN * L_);

  // stage: 3 planes x 64 c x 16 float4
#pragma unroll
  for (int it = 0; it < 12; ++it) {
    int idx = threadIdx.x + it * 256;        // < 3072
    int plane = idx >> 10;
    int rem = idx & 1023;
    int c = rem >> 4;
    int f4 = rem & 15;
    int y = h + plane - 1;
    int e = XS_OFF + plane * XS_PLANE + c * XS_STRIDE + f4 * 4;
    bf16x2 lo = {(bf16)0.f, (bf16)0.f}, hi = {(bf16)0.f, (bf16)0.f};
    if ((unsigned)y < 64u) {
      float4 v = *(const float4*)(x + bOff + (size_t)c * L_ + y * 64 + f4 * 4);
      lo = bf16x2{(bf16)v.x, (bf16)v.y};
      hi = bf16x2{(bf16)v.z, (bf16)v.w};
    }
    *(bf16x2*)(xs + e) = lo;
    *(bf16x2*)(xs + e + 2) = hi;
  }
  __syncthreads();

  const int lane = threadIdx.x & 63, wid = threadIdx.x >> 6;
  // per-lane constants: main segment p = lane*8 + q
  int eb[8], km[8];
#pragma unroll
  for (int q = 0; q < 8; q++) {
    int p = lane * 8 + q;
    int c = p / 9, r9 = p - c * 9;
    int kh = r9 / 3, kw = r9 - kh * 3;
    eb[q] = kh * XS_PLANE + c * XS_STRIDE + (kw - 1);
    km[q] = kw - 1;
  }
  // tail segment (lanes 0..7): p = 512 + lane*8 + q
  int ebt[8], kmt[8];
  {
    int pl = (lane & 7) * 8;  // keep indices sane for all lanes; only lane<8 reads
#pragma unroll
    for (int q = 0; q < 8; q++) {
      int p = 512 + pl + q;
      int c = p / 9, r9 = p - c * 9;
      int kh = r9 / 3, kw = r9 - kh * 3;
      ebt[q] = kh * XS_PLANE + c * XS_STRIDE + (kw - 1);
      kmt[q] = kw - 1;
    }
  }

  for (int it = 0; it < 16; ++it) {
    int w = wid * 16 + it;
    int row = bh * 64 + w;
    bf16* outp = flatB + (size_t)row * PS;
    float s = 0.f;
    bf16x8 v;
#pragma unroll
    for (int q = 0; q < 8; q++) {
      int xx = w + km[q];
      float fv = ((unsigned)xx < 64u) ? (float)xs[XS_OFF + eb[q] + w] : 0.f;
      v[q] = (bf16)fv;
      s += fv * fv;
    }
    *(bf16x8*)(outp + lane * 8) = v;
    if (lane < 8) {
      bf16x8 v2;
#pragma unroll
      for (int q = 0; q < 8; q++) {
        int xx = w + kmt[q];
        float fv = ((unsigned)xx < 64u) ? (float)xs[XS_OFF + ebt[q] + w] : 0.f;
        v2[q] = (bf16)fv;
        s += fv * fv;
      }
      *(bf16x8*)(outp + 512 + lane * 8) = v2;
    }
    for (int o = 32; o; o >>= 1) s += __shfl_xor(s, o);
    if (lane == 0) { rn[row] = s; rsum[row] = 0.f; }
  }
}

// VT[b][l'][p'] = final_b viewed as [576][4096] at [p'][l'], with boundary mask.
// grid (64, 9, B_)
__global__ void transpose_mask_kernel(const bf16* __restrict__ finalB, bf16* __restrict__ VT) {
  int b = blockIdx.z;
  int l0 = blockIdx.x * 64, p0 = blockIdx.y * 64;
  const bf16* src = finalB + (size_t)b * L_ * PS;
  bf16* dst = VT + (size_t)b * L_ * PS;
  __shared__ bf16 tile[64][72];
  for (int s = threadIdx.x; s < 512; s += 256) {
    int i = s >> 3, ch = s & 7;  // i: p-row in tile, ch: l-chunk
    bf16x8 v = *(const bf16x8*)(src + (size_t)(p0 + i) * L_ + l0 + ch * 8);
#pragma unroll
    for (int q = 0; q < 8; q++) tile[ch * 8 + q][i] = v[q];
  }
  __syncthreads();
  for (int s = threadIdx.x; s < 512; s += 256) {
    int r = s >> 3, c = s & 7;  // r: l-row in tile, c: p-chunk
    int l = l0 + r;
    int oh = l >> 6, ow = l & 63;
    bf16x8 v;
#pragma unroll
    for (int q = 0; q < 8; q++) {
      int p = p0 + c * 8 + q;
      int r9 = p % 9;
      int kh = r9 / 3, kw = r9 - kh * 3;
      bf16 val = tile[r][c * 8 + q];
      if ((oh == 0 && kh == 0) || (ow == 0 && kw == 0)) val = (bf16)0.f;
      v[q] = val;
    }
    *(bf16x8*)(dst + (size_t)l * PS + p0 + c * 8) = v;
  }
}

// ---------------- NT-GEMM: C[M,N] = A[M,K] * B[N,K]^T ----------------
// Round-9 structure (best measured): single-buffer BK=64, 2 __syncthreads per
// K-step, 32 KB LDS, launch_bounds(256,4). LDS row-major [128][64], 8x16B
// slots/row; slot s of row r holds global k-chunk (s ^ (r&7)); write side via
// pre-swizzled global source (gload_lds dest linear), read side same XOR.
// EPI 1: fused softmax-numerator: E = exp(-t*dist) (bf16), atomicAdd row sums.
// EPI 2: final = (t*acc/rsum[row] + flat)/(t+1) -> bf16, in-place over flat.
// EPI 3: batched (z), acc + bias[row] -> fp32 out.
// GX>0: 1D grid, XCD-aware swizzle (n-tiles of one row-panel share an XCD).
template <int EPI, int GX = 0>
__global__ void __launch_bounds__(256, 4) gemm_nt(
    const bf16* __restrict__ A, int lda, const bf16* __restrict__ Bm, int ldb,
    int M, int N, int Kd,
    const float* __restrict__ e0, const float* __restrict__ e1,
    const float* __restrict__ e2, const bf16* flatB,
    float* outF, bf16* outB, int ldc) {
  int bx, by;
  if constexpr (GX > 0) {
    int b = blockIdx.x;
    int xcd = b & 7;
    int k = b >> 3;
    int ypx = (gridDim.x >> 3) / GX;   // row-panels per XCD
    bx = k % GX;
    by = xcd * ypx + k / GX;
  } else {
    bx = blockIdx.x;
    by = blockIdx.y;
  }
  if constexpr (EPI == 3) {
    size_t bz = blockIdx.z;
    Bm += bz * (size_t)L_ * PS;
    outF += bz * (size_t)C_OUT * L_;
  }
  __shared__ bf16 As[128 * 64];   // 16 KB
  __shared__ bf16 Bs[128 * 64];   // 16 KB
  const int tid = threadIdx.x;
  const int lane = tid & 63;
  const int wid = tid >> 6;
  const int wr = wid >> 1, wc = wid & 1;
  const int m0 = by * 128, n0 = bx * 128;

  // staging: thread t covers row r = t>>3 (+32 per issue q), 16B slot s = t&7.
  // source k-chunk pre-inverse-swizzled: chunk = s ^ (r&7).
  const int srow = tid >> 3;
  const int sch = ((tid & 7) ^ (srow & 7)) * 8;
  const bf16* gA = A + (size_t)(m0 + srow) * lda + sch;
  const bf16* gB = Bm + (size_t)(n0 + srow) * ldb + sch;
  bf16* lA = As + tid * 8;
  bf16* lB = Bs + tid * 8;

  const int lrow = lane & 15;
  const int kq = lane >> 4;          // k-quarter within a 32-wide half
  const int axor = lrow & 7;         // read-side slot XOR (row & 7)
  const int arow = (wr * 64 + lrow) * 64;
  const int brow = (wc * 64 + lrow) * 64;

  f32x4 acc[4][4];
#pragma unroll
  for (int i = 0; i < 4; i++)
#pragma unroll
    for (int j = 0; j < 4; j++) acc[i][j] = f32x4{0.f, 0.f, 0.f, 0.f};

  const int nk = Kd >> 6;
  for (int kt = 0; kt < nk; ++kt) {
    __syncthreads();
    const bf16* ga = gA + kt * 64;
    const bf16* gb = gB + kt * 64;
#pragma unroll
    for (int q = 0; q < 4; ++q) {
      gload_lds16(ga + (size_t)(q * 32) * lda, lA + q * 2048);
      gload_lds16(gb + (size_t)(q * 32) * ldb, lB + q * 2048);
    }
    __syncthreads();  // drains vmcnt -> LDS tile ready
#pragma unroll
    for (int h = 0; h < 2; ++h) {
      const int cs = ((h * 4 + kq) ^ axor) * 8;   // swizzled slot for this k-half
      bf16x8 af[4], bfr[4];
#pragma unroll
      for (int i = 0; i < 4; i++) af[i] = *(const bf16x8*)(As + arow + i * 1024 + cs);
#pragma unroll
      for (int j = 0; j < 4; j++) bfr[j] = *(const bf16x8*)(Bs + brow + j * 1024 + cs);
#pragma unroll
      for (int i = 0; i < 4; i++)
#pragma unroll
        for (int j = 0; j < 4; j++)
          acc[i][j] = __builtin_amdgcn_mfma_f32_16x16x32_bf16(af[i], bfr[j], acc[i][j], 0, 0, 0);
    }
  }

  const int rb = m0 + wr * 64 + kq * 4;  // D row = (lane>>4)*4 + reg
  const int cb = n0 + wc * 64 + lrow;    // D col = lane&15
  if constexpr (EPI == 1) {
    // e0 = rn, e1 = cn, e2 = temp; outB = E (bf16), outF = rsum (fp32 atomics)
    float t = e2[0];
#pragma unroll
    for (int i = 0; i < 4; i++) {
      float rowsum[4] = {0.f, 0.f, 0.f, 0.f};
#pragma unroll
      for (int j = 0; j < 4; j++) {
        int col = cb + j * 16;
        float cnv = e1[col];
#pragma unroll
        for (int r = 0; r < 4; r++) {
          int row = rb + i * 16 + r;
          float d2 = e0[row] + cnv - 2.f * acc[i][j][r];
          float e = __expf(-t * sqrtf(fmaxf(d2, 0.f)));
          outB[(size_t)row * ldc + col] = (bf16)e;
          rowsum[r] += e;
        }
      }
#pragma unroll
      for (int r = 0; r < 4; r++) {
        float s = rowsum[r];
        s += __shfl_xor(s, 1);
        s += __shfl_xor(s, 2);
        s += __shfl_xor(s, 4);
        s += __shfl_xor(s, 8);
        if (lrow == 0) atomicAdd(outF + rb + i * 16 + r, s);
      }
    }
  } else if constexpr (EPI == 2) {
    // e0 = temp, e1 = rsum; flatB = flat (read), outB = flat (in-place write)
    float t = e0[0];
    float inv = 1.f / (t + 1.f);
#pragma unroll
    for (int i = 0; i < 4; i++) {
      float arw[4];
#pragma unroll
      for (int r = 0; r < 4; r++) arw[r] = t * inv / e1[rb + i * 16 + r];
#pragma unroll
      for (int j = 0; j < 4; j++) {
        int col = cb + j * 16;
        if (col < N) {
#pragma unroll
          for (int r = 0; r < 4; r++) {
            int row = rb + i * 16 + r;
            float fl = (float)flatB[(size_t)row * PS + col];
            float v = acc[i][j][r] * arw[r] + fl * inv;
            outB[(size_t)row * ldc + col] = (bf16)v;
          }
        }
      }
    }
  } else {
    // e0 = bias; outF = out
#pragma unroll
    for (int i = 0; i < 4; i++) {
#pragma unroll
      for (int j = 0; j < 4; j++) {
        int col = cb + j * 16;
#pragma unroll
        for (int r = 0; r < 4; r++) {
          int row = rb + i * 16 + r;
          outF[(size_t)row * ldc + col] = acc[i][j][r] + e0[row];
        }
      }
    }
  }
}

// ---------------- launch ----------------

extern "C" void kernel_launch(void* const* d_in, const int* in_sizes, int n_in,
                              void* d_out, int out_size, void* d_ws, size_t ws_size,
                              hipStream_t stream) {
  (void)in_sizes; (void)n_in; (void)out_size; (void)ws_size;
  const float* x    = (const float*)d_in[0];
  const float* cc   = (const float*)d_in[1];
  const float* tp   = (const float*)d_in[2];
  const float* w    = (const float*)d_in[3];
  const float* bias = (const float*)d_in[4];
  float* out = (float*)d_out;

  char* ws = (char*)d_ws;
  size_t off = 0;
  auto alloc = [&](size_t bytes) {
    char* p = ws + off;
    off += (bytes + 255) & ~(size_t)255;
    return p;
  };
  // small persistent buffers
  bf16* ccB   = (bf16*)alloc((size_t)NC * PS * 2);        // 0.59 MB
  bf16* ccT   = (bf16*)alloc((size_t)640 * NC * 2);       // 0.66 MB (576 rows + 64 zero pad)
  float* cn   = (float*)alloc((size_t)NC * 4);
  bf16* WB    = (bf16*)alloc((size_t)C_OUT * PS * 2);     // 0.15 MB
  float* rn   = (float*)alloc((size_t)NR * 4);            // 0.26 MB
  float* rsum = (float*)alloc((size_t)NR * 4);            // 0.26 MB
  bf16* flatB = (bf16*)alloc((size_t)NR * PS * 2);        // 75.5 MB (final written in-place)
  char* Ereg  = alloc((size_t)NR * PS * 2);               // 75.5 MB region: E (65536x512) then VT
  bf16* E  = (bf16*)Ereg;
  bf16* VT = (bf16*)Ereg;
  // total ~= 153 MB  (ws_size = 256 MiB)

  prep_w_kernel<<<dim3(288), dim3(256), 0, stream>>>(w, WB, ccT);
  prep_cc_kernel<<<dim3(NC), dim3(256), 0, stream>>>(cc, ccB, ccT, cn);
  patch_kernel<<<dim3(B_ * H_), dim3(256), 0, stream>>>(x, flatB, rn, rsum);
  // GEMM1 (+softmax numerator): E = exp(-t*sqrt(max(rn+cn-2*flat@cc^T,0))), rsum += rows
  gemm_nt<1, 4><<<dim3((NC / 128) * (NR / 128)), dim3(256), 0, stream>>>(
      flatB, PS, ccB, PS, NR, NC, PS, rn, cn, tp, nullptr, rsum, E, NC);
  // GEMM2: flat <- (t*(E@cc)/rsum + flat)/(t+1)   (in-place)
  gemm_nt<2, 5><<<dim3(5 * (NR / 128)), dim3(256), 0, stream>>>(
      E, NC, ccT, NC, NR, PS, NC, tp, rsum, nullptr, flatB, nullptr, flatB, PS);
  transpose_mask_kernel<<<dim3(64, 9, B_), dim3(256), 0, stream>>>(flatB, VT);
  // GEMM3 (batched): out[b] = W' @ Vmask_b + bias
  gemm_nt<3><<<dim3(L_ / 128, 1, B_), dim3(256), 0, stream>>>(
      WB, PS, VT, PS, C_OUT, L_, PS, bias, nullptr, nullptr, nullptr, out, nullptr, L_);
}